// Round 9
// baseline (2011.639 us; speedup 1.0000x reference)
//
#include <hip/hip_runtime.h>
#include <stdint.h>

#define MROWS  200704
#define SCALE_ 0.17677669529663687f  // 32^-0.5

typedef __attribute__((ext_vector_type(8))) short bf16x8;
typedef __attribute__((ext_vector_type(4))) float f32x4;
union V8 { uint4 u; unsigned short s[8]; };

__device__ __forceinline__ float bf2f(unsigned short u) {
  union { unsigned int i; float f; } c; c.i = ((unsigned int)u) << 16; return c.f;
}
__device__ __forceinline__ unsigned short f2bf(float f) {
  union { float f; unsigned int i; } c; c.f = f;
  unsigned int lsb = (c.i >> 16) & 1;
  return (unsigned short)((c.i + 0x7fffu + lsb) >> 16);
}
// tanh-form GELU, exp-based; validated round 5/7
__device__ __forceinline__ float gelu_f(float x) {
  float x2 = x * x;
  float arg = x * fmaf(0.07135481f, x2, 1.59576912f);
  float e = __expf(arg);
  float r = __builtin_amdgcn_rcpf(1.0f + e);
  return fmaf(-x, r, x);
}

// ---------------- weight convert+transpose: W (K x N fp32) -> Wt (N x K bf16) ----------------
__global__ __launch_bounds__(256) void wt_k(const float* __restrict__ W,
    unsigned short* __restrict__ Wt, int K, int N)
{
  int idx = blockIdx.x * 256 + threadIdx.x;
  if (idx < K * N) {
    int k = idx / N, n = idx - k * N;
    Wt[(size_t)n * K + k] = f2bf(W[idx]);
  }
}

// ---------------- LayerNorm + shifted window partition ----------------
__global__ __launch_bounds__(256) void ln_k(const float* __restrict__ X,
    const float* __restrict__ g, const float* __restrict__ b,
    unsigned short* __restrict__ out, int shift)
{
  int wr = blockIdx.x * 4 + (threadIdx.x >> 6);
  int lane = threadIdx.x & 63;
  int win = wr / 49, n = wr % 49;
  int bi = win >> 6, w64 = win & 63;
  int wh = w64 >> 3, ww = w64 & 7;
  int ti = n / 7, tj = n % 7;
  int gh = wh * 7 + ti + shift; if (gh >= 56) gh -= 56;
  int gw = ww * 7 + tj + shift; if (gw >= 56) gw -= 56;
  size_t srow = (size_t)bi * 3136 + gh * 56 + gw;
  const float* xr = X + srow * 192;
  float v0 = xr[lane], v1 = xr[lane + 64], v2 = xr[lane + 128];
  float s  = v0 + v1 + v2;
  float s2 = v0*v0 + v1*v1 + v2*v2;
  #pragma unroll
  for (int m = 32; m >= 1; m >>= 1) { s += __shfl_xor(s, m); s2 += __shfl_xor(s2, m); }
  float mean = s * (1.0f/192.0f);
  float var  = s2 * (1.0f/192.0f) - mean*mean;
  float inv  = rsqrtf(var + 1e-5f);
  unsigned short* orow = out + (size_t)wr * 192;
  orow[lane]       = f2bf((v0-mean)*inv*g[lane]      + b[lane]);
  orow[lane+64]    = f2bf((v1-mean)*inv*g[lane+64]   + b[lane+64]);
  orow[lane+128]   = f2bf((v2-mean)*inv*g[lane+128]  + b[lane+128]);
}

// ---------------- MFMA GEMM (K=192) ----------------
// Grid is (panel, rowblock): blocks sharing an A-tile are dispatch-adjacent -> L2 reuse.
// B fragments preloaded before the k-loop; A-stage regs double-buffered.
// EPI: 0 = write bf16 (qkv); 1 = proj: window-reverse scatter + residual (N==192)
template<int EPI>
__global__ __launch_bounds__(256, 4) void gemm2_k(
    const unsigned short* __restrict__ A,
    const unsigned short* __restrict__ Wt,   // [N][192] bf16
    const float* __restrict__ bias,
    unsigned short* __restrict__ Cbf,
    const float* __restrict__ Xres,
    float* __restrict__ Xdst,
    int N, int shift)
{
  __shared__ unsigned short As[128][40];   // pad 40: 2-way banked reads (free)
  const int tid = threadIdx.x;
  const int lane = tid & 63, wv = tid >> 6;
  const int wm = wv >> 1, wn = wv & 1;     // 2x2 waves over 128x64 tile
  const int row0 = blockIdx.y * 128;
  const int n0   = blockIdx.x * 64;
  const int fr = lane & 15, kq = (lane >> 4) * 8;
  bf16x8 bfr[6][2];
  #pragma unroll
  for (int ks = 0; ks < 6; ++ks)
    #pragma unroll
    for (int ni = 0; ni < 2; ++ni)
      bfr[ks][ni] = *reinterpret_cast<const bf16x8*>(
          &Wt[(size_t)(n0 + wn*32 + ni*16 + fr) * 192 + ks*32 + kq]);
  const int sr  = tid >> 1, ssg = (tid & 1) * 16;
  const unsigned short* arow = A + (size_t)(row0 + sr) * 192 + ssg;
  uint4 a0 = *reinterpret_cast<const uint4*>(arow);
  uint4 a1 = *reinterpret_cast<const uint4*>(arow + 8);
  f32x4 acc[4][2] = {};
  #pragma unroll
  for (int ks = 0; ks < 6; ++ks) {
    __syncthreads();
    *reinterpret_cast<uint4*>(&As[sr][ssg])     = a0;
    *reinterpret_cast<uint4*>(&As[sr][ssg + 8]) = a1;
    if (ks < 5) {
      a0 = *reinterpret_cast<const uint4*>(arow + (ks+1)*32);
      a1 = *reinterpret_cast<const uint4*>(arow + (ks+1)*32 + 8);
    }
    __syncthreads();
    #pragma unroll
    for (int mi = 0; mi < 4; ++mi) {
      bf16x8 afr = *reinterpret_cast<const bf16x8*>(&As[wm*64 + mi*16 + fr][kq]);
      #pragma unroll
      for (int ni = 0; ni < 2; ++ni)
        acc[mi][ni] = __builtin_amdgcn_mfma_f32_16x16x32_bf16(afr, bfr[ks][ni], acc[mi][ni], 0, 0, 0);
    }
  }
  const int lcol = lane & 15, lr4 = (lane >> 4) * 4;
  #pragma unroll
  for (int mi = 0; mi < 4; ++mi)
  #pragma unroll
  for (int ni = 0; ni < 2; ++ni)
  #pragma unroll
  for (int i = 0; i < 4; ++i) {
    int gr = row0 + wm*64 + mi*16 + lr4 + i;
    int gc = n0 + wn*32 + ni*16 + lcol;
    float v = acc[mi][ni][i] + bias[gc];
    if (EPI == 0) {
      Cbf[(size_t)gr * N + gc] = f2bf(v);
    } else {
      int win = gr / 49, n = gr % 49;
      int bi = win >> 6, w64 = win & 63;
      int wh = w64 >> 3, ww = w64 & 7;
      int ti = n / 7, tj = n % 7;
      int gh = wh*7 + ti + shift; if (gh >= 56) gh -= 56;
      int gw = ww*7 + tj + shift; if (gw >= 56) gw -= 56;
      size_t idx = ((size_t)bi * 3136 + gh * 56 + gw) * 192 + gc;
      Xdst[idx] = Xres[idx] + v;
    }
  }
}

// ---------------- Fused LN2 + FC1 + GELU + FC2 + residual ----------------
// r7 structure (512 thr, 64 rows, 8 waves, inline weight loads) but H processed
// in FOUR 192-col quarters: LDS 76.3 -> 51.2 KB => 3 blocks/CU (was 2).
__global__ __launch_bounds__(512, 6) void mlp_k(
    const float* __restrict__ X,
    const float* __restrict__ g, const float* __restrict__ b,
    const unsigned short* __restrict__ W1t, // [768][192] bf16
    const float* __restrict__ b1,
    const unsigned short* __restrict__ W2t, // [192][768] bf16
    const float* __restrict__ b2,
    float* __restrict__ Y)
{
  __shared__ unsigned short As[64][200];
  __shared__ unsigned short Hs[64][200];
  const int row0 = blockIdx.x * 64;
  const int tid = threadIdx.x, lane = tid & 63, wv = tid >> 6;
  #pragma unroll
  for (int r = 0; r < 8; ++r) {
    int row = wv * 8 + r;
    const float* xr = X + (size_t)(row0 + row) * 192;
    float v0 = xr[lane], v1 = xr[lane + 64], v2 = xr[lane + 128];
    float s  = v0 + v1 + v2;
    float s2 = v0*v0 + v1*v1 + v2*v2;
    #pragma unroll
    for (int m = 32; m >= 1; m >>= 1) { s += __shfl_xor(s, m); s2 += __shfl_xor(s2, m); }
    float mean = s * (1.0f/192.0f);
    float var  = s2 * (1.0f/192.0f) - mean*mean;
    float inv  = rsqrtf(var + 1e-5f);
    As[row][lane]       = f2bf((v0-mean)*inv*g[lane]      + b[lane]);
    As[row][lane+64]    = f2bf((v1-mean)*inv*g[lane+64]   + b[lane+64]);
    As[row][lane+128]   = f2bf((v2-mean)*inv*g[lane+128]  + b[lane+128]);
  }
  __syncthreads();
  const int fr = lane & 15, kq = (lane >> 4) * 8;
  const int lcol = lane & 15, lr4 = (lane >> 4) * 4;
  const int wm = wv >> 2, wn = wv & 3;    // 2 x 4 wave grid (FC1 and FC2)
  f32x4 acc2[2][3] = {};
  for (int q = 0; q < 4; ++q) {
    // ---- FC1 quarter: rows wm*32..+31, h-cols q*192 + wn*48..+47
    f32x4 acc1[2][3] = {};
    #pragma unroll
    for (int ks = 0; ks < 6; ++ks) {
      bf16x8 bfr[3];
      #pragma unroll
      for (int ni = 0; ni < 3; ++ni)
        bfr[ni] = *reinterpret_cast<const bf16x8*>(
            &W1t[(size_t)(q*192 + wn*48 + ni*16 + fr) * 192 + ks*32 + kq]);
      #pragma unroll
      for (int mi = 0; mi < 2; ++mi) {
        bf16x8 afr = *reinterpret_cast<const bf16x8*>(&As[wm*32 + mi*16 + fr][ks*32 + kq]);
        #pragma unroll
        for (int ni = 0; ni < 3; ++ni)
          acc1[mi][ni] = __builtin_amdgcn_mfma_f32_16x16x32_bf16(afr, bfr[ni], acc1[mi][ni], 0, 0, 0);
      }
    }
    __syncthreads();   // previous quarter's FC2 done reading Hs
    // ---- GELU -> Hs quarter
    #pragma unroll
    for (int mi = 0; mi < 2; ++mi)
    #pragma unroll
    for (int ni = 0; ni < 3; ++ni)
    #pragma unroll
    for (int i = 0; i < 4; ++i) {
      int rr = wm*32 + mi*16 + lr4 + i;
      int cc = wn*48 + ni*16 + lcol;
      float v = acc1[mi][ni][i] + b1[q*192 + cc];
      Hs[rr][cc] = f2bf(gelu_f(v));
    }
    __syncthreads();   // Hs quarter ready
    // ---- FC2 partial over this quarter's 192 h's
    #pragma unroll
    for (int ks = 0; ks < 6; ++ks) {
      bf16x8 bfr[3];
      #pragma unroll
      for (int ni = 0; ni < 3; ++ni)
        bfr[ni] = *reinterpret_cast<const bf16x8*>(
            &W2t[(size_t)(wn*48 + ni*16 + fr) * 768 + q*192 + ks*32 + kq]);
      #pragma unroll
      for (int mi = 0; mi < 2; ++mi) {
        bf16x8 afr = *reinterpret_cast<const bf16x8*>(&Hs[wm*32 + mi*16 + fr][ks*32 + kq]);
        #pragma unroll
        for (int ni = 0; ni < 3; ++ni)
          acc2[mi][ni] = __builtin_amdgcn_mfma_f32_16x16x32_bf16(afr, bfr[ni], acc2[mi][ni], 0, 0, 0);
      }
    }
  }
  #pragma unroll
  for (int mi = 0; mi < 2; ++mi)
  #pragma unroll
  for (int ni = 0; ni < 3; ++ni)
  #pragma unroll
  for (int i = 0; i < 4; ++i) {
    int grow = row0 + wm*32 + mi*16 + lr4 + i;
    int gc = wn*48 + ni*16 + lcol;
    float v = acc2[mi][ni][i] + b2[gc];
    size_t idx = (size_t)grow * 192 + gc;
    Y[idx] = X[idx] + v;
  }
}

// ---------------- Windowed attention: one wave per (window, head) ----------------
template<bool SHIFTED>
__global__ __launch_bounds__(64) void attn_k(
    const unsigned short* __restrict__ qkv,
    const float* __restrict__ rpb,
    unsigned short* __restrict__ out)
{
  __shared__ float kv[2][49][32];
  int blk = blockIdx.x;
  int win = blk / 6, h = blk - win * 6;
  int lane = threadIdx.x;
  const unsigned short* base = qkv + (size_t)win * 49 * 576;
  for (int idx = lane; idx < 196; idx += 64) {
    int n = idx >> 2, sg = (idx & 3) * 8;
    V8 kk, vv;
    kk.u = *reinterpret_cast<const uint4*>(base + n*576 + 192 + h*32 + sg);
    vv.u = *reinterpret_cast<const uint4*>(base + n*576 + 384 + h*32 + sg);
    #pragma unroll
    for (int j = 0; j < 8; ++j) { kv[0][n][sg+j] = bf2f(kk.s[j]); kv[1][n][sg+j] = bf2f(vv.s[j]); }
  }
  __syncthreads();
  if (lane < 49) {
    float q[32];
    const unsigned short* qr = base + (size_t)lane * 576 + h * 32;
    #pragma unroll
    for (int sg = 0; sg < 4; ++sg) {
      V8 qq; qq.u = *reinterpret_cast<const uint4*>(qr + sg*8);
      #pragma unroll
      for (int j = 0; j < 8; ++j) q[sg*8+j] = bf2f(qq.s[j]) * SCALE_;
    }
    int ti = lane / 7, tj = lane - ti * 7;
    int wi = win & 63, wh = wi >> 3, ww = wi & 7;
    int rid = 0;
    if (SHIFTED) {
      int hh = wh*7 + ti, wg = ww*7 + tj;
      rid = (hh < 49 ? 0 : (hh < 53 ? 1 : 2)) * 3 + (wg < 49 ? 0 : (wg < 53 ? 1 : 2));
    }
    float s[49];
    float mx = -1e30f;
    #pragma unroll
    for (int m = 0; m < 49; ++m) {
      float a = 0.f;
      #pragma unroll
      for (int d4 = 0; d4 < 8; ++d4) {
        float4 kf = *reinterpret_cast<const float4*>(&kv[0][m][d4*4]);
        a += q[d4*4+0]*kf.x + q[d4*4+1]*kf.y + q[d4*4+2]*kf.z + q[d4*4+3]*kf.w;
      }
      int mi = m / 7, mj = m - mi * 7;
      a += rpb[((ti - mi + 6) * 13 + (tj - mj + 6)) * 6 + h];
      if (SHIFTED) {
        int hh = wh*7 + mi, wg = ww*7 + mj;
        int rid2 = (hh < 49 ? 0 : (hh < 53 ? 1 : 2)) * 3 + (wg < 49 ? 0 : (wg < 53 ? 1 : 2));
        if (rid2 != rid) a -= 100.f;
      }
      s[m] = a;
      mx = fmaxf(mx, a);
    }
    float sum = 0.f;
    #pragma unroll
    for (int m = 0; m < 49; ++m) { float e = __expf(s[m] - mx); s[m] = e; sum += e; }
    float rs = 1.f / sum;
    float o[32];
    #pragma unroll
    for (int d = 0; d < 32; ++d) o[d] = 0.f;
    #pragma unroll
    for (int m = 0; m < 49; ++m) {
      float p = s[m] * rs;
      #pragma unroll
      for (int d4 = 0; d4 < 8; ++d4) {
        float4 vf = *reinterpret_cast<const float4*>(&kv[1][m][d4*4]);
        o[d4*4+0] += p*vf.x; o[d4*4+1] += p*vf.y; o[d4*4+2] += p*vf.z; o[d4*4+3] += p*vf.w;
      }
    }
    unsigned short* orow = out + ((size_t)win * 49 + lane) * 192 + h * 32;
    #pragma unroll
    for (int sg = 0; sg < 4; ++sg) {
      V8 pk;
      #pragma unroll
      for (int j = 0; j < 8; ++j) pk.s[j] = f2bf(o[sg*8+j]);
      *reinterpret_cast<uint4*>(orow + sg*8) = pk.u;
    }
  }
}

// ---------------- launch ----------------
extern "C" void kernel_launch(void* const* d_in, const int* in_sizes, int n_in,
                              void* d_out, int out_size, void* d_ws, size_t ws_size,
                              hipStream_t stream) {
  const float* x    = (const float*)d_in[0];
  const float* n1g  = (const float*)d_in[1];
  const float* n1b  = (const float*)d_in[2];
  const float* qkvw = (const float*)d_in[3];
  const float* qkvb = (const float*)d_in[4];
  const float* rpb  = (const float*)d_in[5];
  const float* pw   = (const float*)d_in[6];
  const float* pb   = (const float*)d_in[7];
  const float* n2g  = (const float*)d_in[8];
  const float* n2b  = (const float*)d_in[9];
  const float* f1w  = (const float*)d_in[10];
  const float* f1b  = (const float*)d_in[11];
  const float* f2w  = (const float*)d_in[12];
  const float* f2b  = (const float*)d_in[13];
  float* out = (float*)d_out;

  const size_t XBYTES = (size_t)MROWS * 192 * 4;
  const size_t ABYTES = (size_t)MROWS * 192 * 2;
  const size_t QBYTES = (size_t)MROWS * 576 * 2;
  char* ws = (char*)d_ws;
  float* x1 = (float*)ws;
  unsigned short* Abuf = (unsigned short*)(ws + XBYTES);
  unsigned short* Bbuf = (unsigned short*)(ws + XBYTES + ABYTES);
  unsigned short* WT   = (unsigned short*)(ws + XBYTES + ABYTES + QBYTES);
  const size_t WQ = 110592, WP = 36864, W1 = 147456, W2 = 147456;
  const size_t WD = WQ + WP + W1 + W2;

  for (int d = 0; d < 2; ++d) {
    unsigned short* wt = WT + d * WD;
    wt_k<<<(int)((WQ + 255)/256), 256, 0, stream>>>(qkvw + (size_t)d*WQ, wt,                 192, 576);
    wt_k<<<(int)((WP + 255)/256), 256, 0, stream>>>(pw   + (size_t)d*WP, wt + WQ,            192, 192);
    wt_k<<<(int)((W1 + 255)/256), 256, 0, stream>>>(f1w  + (size_t)d*W1, wt + WQ + WP,       192, 768);
    wt_k<<<(int)((W2 + 255)/256), 256, 0, stream>>>(f2w  + (size_t)d*W2, wt + WQ + WP + W1,  768, 192);
  }

  const int LNBLK = MROWS / 4;
  const dim3 G_QKV(9, MROWS/128), G_P(3, MROWS/128);   // (panel, rowblock)

  for (int i = 0; i < 2; ++i) {
    int shift = i ? 3 : 0;
    const float* xin = i ? (const float*)x1 : x;
    float* xfin = i ? out : x1;
    const unsigned short* wt = WT + i * WD;
    // 1. LN1 + shifted window partition -> Abuf
    ln_k<<<LNBLK, 256, 0, stream>>>(xin, n1g + i*192, n1b + i*192, Abuf, shift);
    // 2. QKV gemm -> Bbuf
    gemm2_k<0><<<G_QKV, 256, 0, stream>>>(Abuf, wt, qkvb + i*576, Bbuf, nullptr, nullptr, 576, 0);
    // 3. attention -> Abuf
    if (shift) attn_k<true ><<<4096*6, 64, 0, stream>>>(Bbuf, rpb + i*169*6, Abuf);
    else       attn_k<false><<<4096*6, 64, 0, stream>>>(Bbuf, rpb + i*169*6, Abuf);
    // 4. proj gemm + window-reverse scatter residual -> x1
    gemm2_k<1><<<G_P, 256, 0, stream>>>(Abuf, wt + WQ, pb + i*192, nullptr, xin, x1, 192, shift);
    // 5. fused LN2 + FC1 + GELU + FC2 + residual
    mlp_k<<<MROWS/64, 512, 0, stream>>>(x1, n2g + i*192, n2b + i*192,
                                        wt + WQ + WP, f1b + i*768,
                                        wt + WQ + WP + W1, f2b + i*192, xfin);
  }
}

// Round 10
// 1836.734 us; speedup vs baseline: 1.0952x; 1.0952x over previous
//
#include <hip/hip_runtime.h>
#include <stdint.h>

#define MROWS  200704
#define SCALE_ 0.17677669529663687f  // 32^-0.5

typedef __attribute__((ext_vector_type(8))) short bf16x8;
typedef __attribute__((ext_vector_type(4))) float f32x4;
union V8 { uint4 u; unsigned short s[8]; };

__device__ __forceinline__ float bf2f(unsigned short u) {
  union { unsigned int i; float f; } c; c.i = ((unsigned int)u) << 16; return c.f;
}
__device__ __forceinline__ unsigned short f2bf(float f) {
  union { float f; unsigned int i; } c; c.f = f;
  unsigned int lsb = (c.i >> 16) & 1;
  return (unsigned short)((c.i + 0x7fffu + lsb) >> 16);
}
// tanh-form GELU, exp-based; validated round 5/7
__device__ __forceinline__ float gelu_f(float x) {
  float x2 = x * x;
  float arg = x * fmaf(0.07135481f, x2, 1.59576912f);
  float e = __expf(arg);
  float r = __builtin_amdgcn_rcpf(1.0f + e);
  return fmaf(-x, r, x);
}

// ---------------- weight convert+transpose: W (K x N fp32) -> Wt (N x K bf16) ----------------
__global__ __launch_bounds__(256) void wt_k(const float* __restrict__ W,
    unsigned short* __restrict__ Wt, int K, int N)
{
  int idx = blockIdx.x * 256 + threadIdx.x;
  if (idx < K * N) {
    int k = idx / N, n = idx - k * N;
    Wt[(size_t)n * K + k] = f2bf(W[idx]);
  }
}

// ---------------- FUSED LN1 (windowed gather) + QKV GEMM ----------------
// Stage the full 128x192 LN'd A-tile in LDS ONCE (one barrier), then 9 output
// panels with no further barriers -> panel p+1's weight loads pipeline under
// panel p's MFMAs.
__global__ __launch_bounds__(256, 3) void qkvf_k(const float* __restrict__ X,
    const float* __restrict__ g, const float* __restrict__ b,
    const unsigned short* __restrict__ Wt,   // [576][192] bf16
    const float* __restrict__ bias,
    unsigned short* __restrict__ C, int shift)
{
  __shared__ unsigned short As[128][200];   // pad 200: 2-way banked b128 reads (free)
  const int tid = threadIdx.x, lane = tid & 63, wv = tid >> 6;
  const int row0 = blockIdx.x * 128;
  #pragma unroll 2
  for (int r = 0; r < 32; ++r) {
    int row = wv * 32 + r, wr = row0 + row;
    int win = wr / 49, n = wr - win * 49;
    int bi = win >> 6, w64 = win & 63, wh = w64 >> 3, ww = w64 & 7;
    int ti = n / 7, tj = n - ti * 7;
    int gh = wh*7 + ti + shift; if (gh >= 56) gh -= 56;
    int gw = ww*7 + tj + shift; if (gw >= 56) gw -= 56;
    const float* xr = X + ((size_t)bi*3136 + gh*56 + gw) * 192;
    float v0 = xr[lane], v1 = xr[lane + 64], v2 = xr[lane + 128];
    float s  = v0 + v1 + v2;
    float s2 = v0*v0 + v1*v1 + v2*v2;
    #pragma unroll
    for (int m = 32; m >= 1; m >>= 1) { s += __shfl_xor(s, m); s2 += __shfl_xor(s2, m); }
    float mean = s * (1.0f/192.0f);
    float var  = s2 * (1.0f/192.0f) - mean*mean;
    float inv  = rsqrtf(var + 1e-5f);
    As[row][lane]     = f2bf((v0-mean)*inv*g[lane]      + b[lane]);
    As[row][lane+64]  = f2bf((v1-mean)*inv*g[lane+64]   + b[lane+64]);
    As[row][lane+128] = f2bf((v2-mean)*inv*g[lane+128]  + b[lane+128]);
  }
  __syncthreads();   // the ONLY barrier
  const int wm = wv >> 1, wn = wv & 1;     // 2x2 waves over 128 x 64-panel
  const int fr = lane & 15, kq = (lane >> 4) * 8;
  const int lr4 = (lane >> 4) * 4;
  #pragma unroll 1
  for (int p = 0; p < 9; ++p) {
    bf16x8 bfr[6][2];
    #pragma unroll
    for (int ks = 0; ks < 6; ++ks)
      #pragma unroll
      for (int ni = 0; ni < 2; ++ni)
        bfr[ks][ni] = *reinterpret_cast<const bf16x8*>(
            &Wt[(size_t)(p*64 + wn*32 + ni*16 + fr) * 192 + ks*32 + kq]);
    f32x4 acc[4][2] = {};
    #pragma unroll
    for (int ks = 0; ks < 6; ++ks)
      #pragma unroll
      for (int mi = 0; mi < 4; ++mi) {
        bf16x8 afr = *reinterpret_cast<const bf16x8*>(&As[wm*64 + mi*16 + fr][ks*32 + kq]);
        #pragma unroll
        for (int ni = 0; ni < 2; ++ni)
          acc[mi][ni] = __builtin_amdgcn_mfma_f32_16x16x32_bf16(afr, bfr[ks][ni], acc[mi][ni], 0, 0, 0);
      }
    #pragma unroll
    for (int mi = 0; mi < 4; ++mi)
    #pragma unroll
    for (int ni = 0; ni < 2; ++ni)
    #pragma unroll
    for (int i = 0; i < 4; ++i) {
      int gr = row0 + wm*64 + mi*16 + lr4 + i;
      int gc = p*64 + wn*32 + ni*16 + fr;
      C[(size_t)gr * 576 + gc] = f2bf(acc[mi][ni][i] + bias[gc]);
    }
  }
}

// ---------------- MFMA GEMM (K=192): proj + window-reverse scatter residual ----------------
// r7-verbatim gemm2 structure (B preload, A-stage dbuf).
__global__ __launch_bounds__(256, 4) void proj_k(
    const unsigned short* __restrict__ A,
    const unsigned short* __restrict__ Wt,   // [192][192] bf16
    const float* __restrict__ bias,
    const float* __restrict__ Xres,
    float* __restrict__ Xdst,
    int shift)
{
  __shared__ unsigned short As[128][40];
  const int tid = threadIdx.x;
  const int lane = tid & 63, wv = tid >> 6;
  const int wm = wv >> 1, wn = wv & 1;
  const int row0 = blockIdx.x * 128;
  const int n0   = blockIdx.y * 64;
  const int fr = lane & 15, kq = (lane >> 4) * 8;
  bf16x8 bfr[6][2];
  #pragma unroll
  for (int ks = 0; ks < 6; ++ks)
    #pragma unroll
    for (int ni = 0; ni < 2; ++ni)
      bfr[ks][ni] = *reinterpret_cast<const bf16x8*>(
          &Wt[(size_t)(n0 + wn*32 + ni*16 + fr) * 192 + ks*32 + kq]);
  const int sr  = tid >> 1, ssg = (tid & 1) * 16;
  const unsigned short* arow = A + (size_t)(row0 + sr) * 192 + ssg;
  uint4 a0 = *reinterpret_cast<const uint4*>(arow);
  uint4 a1 = *reinterpret_cast<const uint4*>(arow + 8);
  f32x4 acc[4][2] = {};
  #pragma unroll
  for (int ks = 0; ks < 6; ++ks) {
    __syncthreads();
    *reinterpret_cast<uint4*>(&As[sr][ssg])     = a0;
    *reinterpret_cast<uint4*>(&As[sr][ssg + 8]) = a1;
    if (ks < 5) {
      a0 = *reinterpret_cast<const uint4*>(arow + (ks+1)*32);
      a1 = *reinterpret_cast<const uint4*>(arow + (ks+1)*32 + 8);
    }
    __syncthreads();
    #pragma unroll
    for (int mi = 0; mi < 4; ++mi) {
      bf16x8 afr = *reinterpret_cast<const bf16x8*>(&As[wm*64 + mi*16 + fr][kq]);
      #pragma unroll
      for (int ni = 0; ni < 2; ++ni)
        acc[mi][ni] = __builtin_amdgcn_mfma_f32_16x16x32_bf16(afr, bfr[ks][ni], acc[mi][ni], 0, 0, 0);
    }
  }
  const int lcol = lane & 15, lr4 = (lane >> 4) * 4;
  #pragma unroll
  for (int mi = 0; mi < 4; ++mi)
  #pragma unroll
  for (int ni = 0; ni < 2; ++ni)
  #pragma unroll
  for (int i = 0; i < 4; ++i) {
    int gr = row0 + wm*64 + mi*16 + lr4 + i;
    int gc = n0 + wn*32 + ni*16 + lcol;
    float v = acc[mi][ni][i] + bias[gc];
    int win = gr / 49, n = gr % 49;
    int bi = win >> 6, w64 = win & 63;
    int wh = w64 >> 3, ww = w64 & 7;
    int ti = n / 7, tj = n % 7;
    int gh = wh*7 + ti + shift; if (gh >= 56) gh -= 56;
    int gw = ww*7 + tj + shift; if (gw >= 56) gw -= 56;
    size_t idx = ((size_t)bi * 3136 + gh * 56 + gw) * 192 + gc;
    Xdst[idx] = Xres[idx] + v;
  }
}

// ---------------- Fused LN2 + FC1 + GELU + FC2 + residual (r7 verbatim) ----------------
__global__ __launch_bounds__(512, 4) void mlp_k(
    const float* __restrict__ X,
    const float* __restrict__ g, const float* __restrict__ b,
    const unsigned short* __restrict__ W1t, // [768][192] bf16
    const float* __restrict__ b1,
    const unsigned short* __restrict__ W2t, // [192][768] bf16
    const float* __restrict__ b2,
    float* __restrict__ Y)
{
  __shared__ unsigned short As[64][200];
  __shared__ unsigned short Hs[64][396];
  const int row0 = blockIdx.x * 64;
  const int tid = threadIdx.x, lane = tid & 63, wv = tid >> 6;
  #pragma unroll
  for (int r = 0; r < 8; ++r) {
    int row = wv * 8 + r;
    const float* xr = X + (size_t)(row0 + row) * 192;
    float v0 = xr[lane], v1 = xr[lane + 64], v2 = xr[lane + 128];
    float s  = v0 + v1 + v2;
    float s2 = v0*v0 + v1*v1 + v2*v2;
    #pragma unroll
    for (int m = 32; m >= 1; m >>= 1) { s += __shfl_xor(s, m); s2 += __shfl_xor(s2, m); }
    float mean = s * (1.0f/192.0f);
    float var  = s2 * (1.0f/192.0f) - mean*mean;
    float inv  = rsqrtf(var + 1e-5f);
    As[row][lane]       = f2bf((v0-mean)*inv*g[lane]      + b[lane]);
    As[row][lane+64]    = f2bf((v1-mean)*inv*g[lane+64]   + b[lane+64]);
    As[row][lane+128]   = f2bf((v2-mean)*inv*g[lane+128]  + b[lane+128]);
  }
  __syncthreads();
  const int fr = lane & 15, kq = (lane >> 4) * 8;
  const int lcol = lane & 15, lr4 = (lane >> 4) * 4;
  const int wm2 = wv >> 2, wn2 = wv & 3;
  f32x4 acc2[2][3] = {};
  for (int hh = 0; hh < 2; ++hh) {
    f32x4 acc1[4][3] = {};
    const int c0 = hh * 384 + wv * 48;
    #pragma unroll
    for (int k0 = 0; k0 < 192; k0 += 32) {
      bf16x8 bfr[3];
      #pragma unroll
      for (int ni = 0; ni < 3; ++ni)
        bfr[ni] = *reinterpret_cast<const bf16x8*>(&W1t[(size_t)(c0 + ni*16 + fr) * 192 + k0 + kq]);
      #pragma unroll
      for (int mi = 0; mi < 4; ++mi) {
        bf16x8 afr = *reinterpret_cast<const bf16x8*>(&As[mi*16 + fr][k0 + kq]);
        #pragma unroll
        for (int ni = 0; ni < 3; ++ni)
          acc1[mi][ni] = __builtin_amdgcn_mfma_f32_16x16x32_bf16(afr, bfr[ni], acc1[mi][ni], 0, 0, 0);
      }
    }
    __syncthreads();
    #pragma unroll
    for (int mi = 0; mi < 4; ++mi)
    #pragma unroll
    for (int ni = 0; ni < 3; ++ni)
    #pragma unroll
    for (int i = 0; i < 4; ++i) {
      int rr = mi*16 + lr4 + i;
      int cc = wv*48 + ni*16 + lcol;
      float v = acc1[mi][ni][i] + b1[hh*384 + cc];
      Hs[rr][cc] = f2bf(gelu_f(v));
    }
    __syncthreads();
    #pragma unroll
    for (int k0 = 0; k0 < 384; k0 += 32) {
      bf16x8 bfr[3];
      #pragma unroll
      for (int ni = 0; ni < 3; ++ni)
        bfr[ni] = *reinterpret_cast<const bf16x8*>(
            &W2t[(size_t)(wn2*48 + ni*16 + fr) * 768 + hh*384 + k0 + kq]);
      #pragma unroll
      for (int mi = 0; mi < 2; ++mi) {
        bf16x8 afr = *reinterpret_cast<const bf16x8*>(&Hs[wm2*32 + mi*16 + fr][k0 + kq]);
        #pragma unroll
        for (int ni = 0; ni < 3; ++ni)
          acc2[mi][ni] = __builtin_amdgcn_mfma_f32_16x16x32_bf16(afr, bfr[ni], acc2[mi][ni], 0, 0, 0);
      }
    }
  }
  #pragma unroll
  for (int mi = 0; mi < 2; ++mi)
  #pragma unroll
  for (int ni = 0; ni < 3; ++ni)
  #pragma unroll
  for (int i = 0; i < 4; ++i) {
    int grow = row0 + wm2*32 + mi*16 + lr4 + i;
    int gc = wn2*48 + ni*16 + lcol;
    float v = acc2[mi][ni][i] + b2[gc];
    size_t idx = (size_t)grow * 192 + gc;
    Y[idx] = X[idx] + v;
  }
}

// ---------------- Windowed attention: one wave per (window, head) ----------------
template<bool SHIFTED>
__global__ __launch_bounds__(64) void attn_k(
    const unsigned short* __restrict__ qkv,
    const float* __restrict__ rpb,
    unsigned short* __restrict__ out)
{
  __shared__ float kv[2][49][32];
  int blk = blockIdx.x;
  int win = blk / 6, h = blk - win * 6;
  int lane = threadIdx.x;
  const unsigned short* base = qkv + (size_t)win * 49 * 576;
  for (int idx = lane; idx < 196; idx += 64) {
    int n = idx >> 2, sg = (idx & 3) * 8;
    V8 kk, vv;
    kk.u = *reinterpret_cast<const uint4*>(base + n*576 + 192 + h*32 + sg);
    vv.u = *reinterpret_cast<const uint4*>(base + n*576 + 384 + h*32 + sg);
    #pragma unroll
    for (int j = 0; j < 8; ++j) { kv[0][n][sg+j] = bf2f(kk.s[j]); kv[1][n][sg+j] = bf2f(vv.s[j]); }
  }
  __syncthreads();
  if (lane < 49) {
    float q[32];
    const unsigned short* qr = base + (size_t)lane * 576 + h * 32;
    #pragma unroll
    for (int sg = 0; sg < 4; ++sg) {
      V8 qq; qq.u = *reinterpret_cast<const uint4*>(qr + sg*8);
      #pragma unroll
      for (int j = 0; j < 8; ++j) q[sg*8+j] = bf2f(qq.s[j]) * SCALE_;
    }
    int ti = lane / 7, tj = lane - ti * 7;
    int wi = win & 63, wh = wi >> 3, ww = wi & 7;
    int rid = 0;
    if (SHIFTED) {
      int hh = wh*7 + ti, wg = ww*7 + tj;
      rid = (hh < 49 ? 0 : (hh < 53 ? 1 : 2)) * 3 + (wg < 49 ? 0 : (wg < 53 ? 1 : 2));
    }
    float s[49];
    float mx = -1e30f;
    #pragma unroll
    for (int m = 0; m < 49; ++m) {
      float a = 0.f;
      #pragma unroll
      for (int d4 = 0; d4 < 8; ++d4) {
        float4 kf = *reinterpret_cast<const float4*>(&kv[0][m][d4*4]);
        a += q[d4*4+0]*kf.x + q[d4*4+1]*kf.y + q[d4*4+2]*kf.z + q[d4*4+3]*kf.w;
      }
      int mi = m / 7, mj = m - mi * 7;
      a += rpb[((ti - mi + 6) * 13 + (tj - mj + 6)) * 6 + h];
      if (SHIFTED) {
        int hh = wh*7 + mi, wg = ww*7 + mj;
        int rid2 = (hh < 49 ? 0 : (hh < 53 ? 1 : 2)) * 3 + (wg < 49 ? 0 : (wg < 53 ? 1 : 2));
        if (rid2 != rid) a -= 100.f;
      }
      s[m] = a;
      mx = fmaxf(mx, a);
    }
    float sum = 0.f;
    #pragma unroll
    for (int m = 0; m < 49; ++m) { float e = __expf(s[m] - mx); s[m] = e; sum += e; }
    float rs = 1.f / sum;
    float o[32];
    #pragma unroll
    for (int d = 0; d < 32; ++d) o[d] = 0.f;
    #pragma unroll
    for (int m = 0; m < 49; ++m) {
      float p = s[m] * rs;
      #pragma unroll
      for (int d4 = 0; d4 < 8; ++d4) {
        float4 vf = *reinterpret_cast<const float4*>(&kv[1][m][d4*4]);
        o[d4*4+0] += p*vf.x; o[d4*4+1] += p*vf.y; o[d4*4+2] += p*vf.z; o[d4*4+3] += p*vf.w;
      }
    }
    unsigned short* orow = out + ((size_t)win * 49 + lane) * 192 + h * 32;
    #pragma unroll
    for (int sg = 0; sg < 4; ++sg) {
      V8 pk;
      #pragma unroll
      for (int j = 0; j < 8; ++j) pk.s[j] = f2bf(o[sg*8+j]);
      *reinterpret_cast<uint4*>(orow + sg*8) = pk.u;
    }
  }
}

// ---------------- launch ----------------
extern "C" void kernel_launch(void* const* d_in, const int* in_sizes, int n_in,
                              void* d_out, int out_size, void* d_ws, size_t ws_size,
                              hipStream_t stream) {
  const float* x    = (const float*)d_in[0];
  const float* n1g  = (const float*)d_in[1];
  const float* n1b  = (const float*)d_in[2];
  const float* qkvw = (const float*)d_in[3];
  const float* qkvb = (const float*)d_in[4];
  const float* rpb  = (const float*)d_in[5];
  const float* pw   = (const float*)d_in[6];
  const float* pb   = (const float*)d_in[7];
  const float* n2g  = (const float*)d_in[8];
  const float* n2b  = (const float*)d_in[9];
  const float* f1w  = (const float*)d_in[10];
  const float* f1b  = (const float*)d_in[11];
  const float* f2w  = (const float*)d_in[12];
  const float* f2b  = (const float*)d_in[13];
  float* out = (float*)d_out;

  const size_t XBYTES = (size_t)MROWS * 192 * 4;
  const size_t ABYTES = (size_t)MROWS * 192 * 2;
  const size_t QBYTES = (size_t)MROWS * 576 * 2;
  char* ws = (char*)d_ws;
  float* x1 = (float*)ws;
  unsigned short* Abuf = (unsigned short*)(ws + XBYTES);
  unsigned short* Bbuf = (unsigned short*)(ws + XBYTES + ABYTES);
  unsigned short* WT   = (unsigned short*)(ws + XBYTES + ABYTES + QBYTES);
  const size_t WQ = 110592, WP = 36864, W1 = 147456, W2 = 147456;
  const size_t WD = WQ + WP + W1 + W2;

  for (int d = 0; d < 2; ++d) {
    unsigned short* wt = WT + d * WD;
    wt_k<<<(int)((WQ + 255)/256), 256, 0, stream>>>(qkvw + (size_t)d*WQ, wt,                 192, 576);
    wt_k<<<(int)((WP + 255)/256), 256, 0, stream>>>(pw   + (size_t)d*WP, wt + WQ,            192, 192);
    wt_k<<<(int)((W1 + 255)/256), 256, 0, stream>>>(f1w  + (size_t)d*W1, wt + WQ + WP,       192, 768);
    wt_k<<<(int)((W2 + 255)/256), 256, 0, stream>>>(f2w  + (size_t)d*W2, wt + WQ + WP + W1,  768, 192);
  }

  const dim3 G_P(MROWS/128, 3);

  for (int i = 0; i < 2; ++i) {
    int shift = i ? 3 : 0;
    const float* xin = i ? (const float*)x1 : x;
    float* xfin = i ? out : x1;
    const unsigned short* wt = WT + i * WD;
    // 1. fused LN1 + window gather + QKV gemm -> Bbuf
    qkvf_k<<<MROWS/128, 256, 0, stream>>>(xin, n1g + i*192, n1b + i*192, wt,
                                          qkvb + i*576, Bbuf, shift);
    // 2. attention -> Abuf
    if (shift) attn_k<true ><<<4096*6, 64, 0, stream>>>(Bbuf, rpb + i*169*6, Abuf);
    else       attn_k<false><<<4096*6, 64, 0, stream>>>(Bbuf, rpb + i*169*6, Abuf);
    // 3. proj gemm + window-reverse scatter residual -> x1
    proj_k<<<G_P, 256, 0, stream>>>(Abuf, wt + WQ, pb + i*192, xin, x1, shift);
    // 4. fused LN2 + FC1 + GELU + FC2 + residual
    mlp_k<<<MROWS/64, 512, 0, stream>>>(x1, n2g + i*192, n2b + i*192,
                                        wt + WQ + WP, f1b + i*768,
                                        wt + WQ + WP + W1, f2b + i*192, xfin);
  }
}